// Round 2
// baseline (1388.620 us; speedup 1.0000x reference)
//
#include <hip/hip_runtime.h>
#include <cfloat>

#define TOKENS 16384   // B*N
#define DDIM   2048
#define NEXP   128
#define KTOP   8
#define MB     32      // tokens per block
#define KB     32      // k per LDS tile
#define NTILES (DDIM / KB)   // 64

// branchless sorted-insert into descending top-8 list.
// strict '>' => ties keep the earlier (lower) index, matching jax.lax.top_k.
__device__ __forceinline__ void insert8(float (&vals)[8], int (&idxs)[8], float v, int e) {
    bool c[8];
#pragma unroll
    for (int p = 0; p < 8; ++p) c[p] = v > vals[p];
#pragma unroll
    for (int p = 7; p >= 1; --p) {
        vals[p] = c[p] ? (c[p - 1] ? vals[p - 1] : v) : vals[p];
        idxs[p] = c[p] ? (c[p - 1] ? idxs[p - 1] : e) : idxs[p];
    }
    vals[0] = c[0] ? v : vals[0];
    idxs[0] = c[0] ? e : idxs[0];
}

__global__ __launch_bounds__(256, 2) void router_kernel(
    const float* __restrict__ x, const float* __restrict__ W,
    const float* __restrict__ b, float* __restrict__ out_gates,
    float* __restrict__ out_idx)
{
    // 40 KB LDS, GEMM tiles overlaid with epilogue scratch -> 2 blocks/CU
    __shared__ __align__(16) char smem[40960];
    float* xs0 = (float*)smem;                // [2][MB*KB]   = 8192 B
    float* ws0 = (float*)(smem + 8192);       // [2][NEXP*KB] = 32768 B
    // epilogue overlay (GEMM tiles dead after final barrier):
    float* lg  = (float*)smem;                // [MB][132]    = 16896 B
    float* plv = (float*)(smem + 16896);      // [MB*8][8]    =  8192 B
    int*   pli = (int*)(smem + 25088);        // [MB*8][8]    =  8192 B

    const int tid  = threadIdx.x;
    const int w    = tid >> 6;          // wave 0..3 -> owns experts [32w, 32w+32)
    const int lane = tid & 63;
    const int eg   = lane & 15;         // expert within wave-group
    const int tg   = lane >> 4;         // token sub-group 0..3
    const int tok0 = blockIdx.x * MB;

    const int e0 = w * 32 + eg;         // this thread's experts: e0, e0+16
    float bv[2];
    bv[0] = b[e0];
    bv[1] = b[e0 + 16];

    float acc[8][2];
#pragma unroll
    for (int i = 0; i < 8; ++i) { acc[i][0] = 0.0f; acc[i][1] = 0.0f; }

    const float4* x4 = (const float4*)x;
    const float4* W4 = (const float4*)W;

    // staging slot assignment (one x float4 + four W float4 per thread)
    const int xm = tid >> 3, xq = tid & 7;
    const size_t xsrc = (size_t)(tok0 + xm) * (DDIM / 4) + xq;
    const int    xdst = xm * KB + 4 * (xq ^ (xm & 7));
    int    wdst[4];
    size_t wsrc[4];
#pragma unroll
    for (int r = 0; r < 4; ++r) {
        int e = r * 32 + (tid >> 3);
        wsrc[r] = (size_t)e * (DDIM / 4) + xq;
        wdst[r] = e * KB + 4 * (xq ^ (e & 7));
    }

    float4 sx, sw[4];

    // ---- prologue: tile 0 ----
    sx = x4[xsrc];
#pragma unroll
    for (int r = 0; r < 4; ++r) sw[r] = W4[wsrc[r]];
    *(float4*)&xs0[xdst] = sx;
#pragma unroll
    for (int r = 0; r < 4; ++r) *(float4*)&ws0[wdst[r]] = sw[r];
    __syncthreads();

    // ---- main K loop ----
    for (int t = 0; t < NTILES; ++t) {
        const float* xsc = xs0 + (t & 1) * (MB * KB);
        const float* wsc = ws0 + (t & 1) * (NEXP * KB);
        const bool more = (t + 1) < NTILES;
        if (more) {
            const int kq0 = (t + 1) * (KB / 4);
            sx = x4[xsrc + kq0];
#pragma unroll
            for (int r = 0; r < 4; ++r) sw[r] = W4[wsrc[r] + kq0];
        }

#pragma unroll
        for (int kq = 0; kq < KB / 4; ++kq) {
            float4 xv[8], wv[2];
#pragma unroll
            for (int i = 0; i < 8; ++i) {
                int m = tg + 4 * i;
                xv[i] = *(const float4*)&xsc[m * KB + 4 * (kq ^ (m & 7))];
            }
#pragma unroll
            for (int j = 0; j < 2; ++j) {
                int e = e0 + 16 * j;
                wv[j] = *(const float4*)&wsc[e * KB + 4 * (kq ^ (eg & 7))];
            }
#pragma unroll
            for (int i = 0; i < 8; ++i)
#pragma unroll
                for (int j = 0; j < 2; ++j) {
                    acc[i][j] += xv[i].x * wv[j].x;
                    acc[i][j] += xv[i].y * wv[j].y;
                    acc[i][j] += xv[i].z * wv[j].z;
                    acc[i][j] += xv[i].w * wv[j].w;
                }
        }

        if (more) {
            float* xsn = xs0 + ((t + 1) & 1) * (MB * KB);
            float* wsn = ws0 + ((t + 1) & 1) * (NEXP * KB);
            *(float4*)&xsn[xdst] = sx;
#pragma unroll
            for (int r = 0; r < 4; ++r) *(float4*)&wsn[wdst[r]] = sw[r];
        }
        __syncthreads();
    }

    // ---- epilogue: logits -> LDS (overlays GEMM tiles; safe after barrier) ----
#pragma unroll
    for (int i = 0; i < 8; ++i) {
        int m = tg + 4 * i;
#pragma unroll
        for (int j = 0; j < 2; ++j)
            lg[m * 132 + e0 + 16 * j] = acc[i][j] + bv[j];
    }
    __syncthreads();

    // ---- partial top-8: 8 threads per token, 16 experts each ----
    {
        int tt = tid >> 3, p = tid & 7;
        float vals[8]; int idxs[8];
#pragma unroll
        for (int k = 0; k < 8; ++k) { vals[k] = -FLT_MAX; idxs[k] = 0; }
        const float* row = &lg[tt * 132 + p * 16];
#pragma unroll
        for (int q = 0; q < 16; ++q)
            insert8(vals, idxs, row[q], p * 16 + q);
#pragma unroll
        for (int k = 0; k < 8; ++k) {
            plv[tid * 8 + k] = vals[k];
            pli[tid * 8 + k] = idxs[k];
        }
    }
    __syncthreads();

    // ---- merge + softmax + index output (1 thread per token) ----
    float g[8]; int fidx[8];
    const bool active = (tid < MB);
    if (active) {
        float vals[8]; int idxs[8];
#pragma unroll
        for (int k = 0; k < 8; ++k) { vals[k] = -FLT_MAX; idxs[k] = 0; }
        for (int p = 0; p < 8; ++p) {
#pragma unroll
            for (int k = 0; k < 8; ++k)
                insert8(vals, idxs, plv[(tid * 8 + p) * 8 + k], pli[(tid * 8 + p) * 8 + k]);
        }
        float mx = vals[0];
        float s = 0.0f;
#pragma unroll
        for (int k = 0; k < 8; ++k) { g[k] = __expf(vals[k] - mx); s += g[k]; }
        float inv = 1.0f / s;
#pragma unroll
        for (int k = 0; k < 8; ++k) { g[k] *= inv; fidx[k] = idxs[k]; }
        // indices written as float values (whole out buffer is read back as f32)
#pragma unroll
        for (int k = 0; k < 8; ++k)
            out_idx[(size_t)(tok0 + tid) * KTOP + k] = (float)idxs[k];
    }
    // zero dense gate rows (plv/pli-based merge doesn't read lg anymore)
    for (int f = tid; f < MB * 132; f += 256) lg[f] = 0.0f;
    __syncthreads();

    if (active) {
#pragma unroll
        for (int k = 0; k < 8; ++k) lg[tid * 132 + fidx[k]] = g[k];
    }
    __syncthreads();

    // ---- coalesced dense copy-out ----
    for (int f = tid; f < MB * (NEXP / 4); f += 256) {
        int m = f >> 5, e4 = f & 31;
        float4 v = *(const float4*)&lg[m * 132 + e4 * 4];
        ((float4*)out_gates)[(size_t)(tok0 + m) * (NEXP / 4) + e4] = v;
    }
}

extern "C" void kernel_launch(void* const* d_in, const int* in_sizes, int n_in,
                              void* d_out, int out_size, void* d_ws, size_t ws_size,
                              hipStream_t stream) {
    const float* x = (const float*)d_in[0];   // [B,N,D] f32
    const float* W = (const float*)d_in[1];   // [E,D]   f32
    const float* b = (const float*)d_in[2];   // [E]     f32

    float* out_gates = (float*)d_out;                       // [B,N,E] f32
    float* out_idx   = out_gates + (size_t)TOKENS * NEXP;   // [B,N,K] as f32

    dim3 grid(TOKENS / MB);   // 512 blocks = 2 per CU
    dim3 block(256);
    router_kernel<<<grid, block, 0, stream>>>(x, W, b, out_gates, out_idx);
}

// Round 3
// 350.272 us; speedup vs baseline: 3.9644x; 3.9644x over previous
//
#include <hip/hip_runtime.h>
#include <cfloat>

#define TOKENS 16384   // B*N
#define DDIM   2048
#define NEXP   128
#define KTOP   8
#define MB     64      // tokens per block
#define KB     32      // k per LDS tile
#define NTILES (DDIM / KB)   // 64

// branchless sorted-insert into descending top-8 list.
// strict '>' => ties keep the earlier (lower) index, matching jax.lax.top_k.
__device__ __forceinline__ void insert8(float (&vals)[8], int (&idxs)[8], float v, int e) {
    bool c[8];
#pragma unroll
    for (int p = 0; p < 8; ++p) c[p] = v > vals[p];
#pragma unroll
    for (int p = 7; p >= 1; --p) {
        vals[p] = c[p] ? (c[p - 1] ? vals[p - 1] : v) : vals[p];
        idxs[p] = c[p] ? (c[p - 1] ? idxs[p - 1] : e) : idxs[p];
    }
    vals[0] = c[0] ? v : vals[0];
    idxs[0] = c[0] ? e : idxs[0];
}

// Thread layout (K-loop): ec = tid&31 -> experts ec+32j (j<4, from LDS),
//                         tr = tid>>5 -> tokens  tr+8i  (i<8, x direct from global,
//                         wave-uniform across the 32 ec-lanes -> coalesced/dedup'd).
// LDS holds ONLY W tiles (double-buffered, XOR-slot swizzle -> uniform bank load).
// VGPR kept moderate; launch_bounds(256,1) = R0's proven no-spill regime.
__global__ __launch_bounds__(256, 1) void router_kernel(
    const float* __restrict__ x, const float* __restrict__ W,
    const float* __restrict__ b, float* __restrict__ out_gates,
    float* __restrict__ out_idx)
{
    // 50176 B LDS: GEMM W-tiles overlaid with epilogue scratch
    __shared__ __align__(16) char smem[50176];
    float* ws0 = (float*)smem;                // [2][128*32] = 32768 B (GEMM phase)
    float* lg  = (float*)smem;                // [64][132]   = 33792 B (epilogue overlay)
    float* plv = (float*)(smem + 33792);      // [256][8] f32 = 8192 B
    int*   pli = (int*)(smem + 41984);        // [256][8] i32 = 8192 B

    const int tid  = threadIdx.x;
    const int ec   = tid & 31;          // expert column
    const int tr   = tid >> 5;          // token row group (0..7)
    const int tok0 = blockIdx.x * MB;

    float bv[4];
#pragma unroll
    for (int j = 0; j < 4; ++j) bv[j] = b[ec + 32 * j];

    float acc[8][4];
#pragma unroll
    for (int i = 0; i < 8; ++i)
#pragma unroll
        for (int j = 0; j < 4; ++j) acc[i][j] = 0.0f;

    const float4* x4 = (const float4*)x;
    const float4* W4 = (const float4*)W;

    // x row pointers (wave-uniform across ec-lanes -> 2 distinct lines/instr)
    const float4* xp[8];
#pragma unroll
    for (int i = 0; i < 8; ++i)
        xp[i] = x4 + (size_t)(tok0 + tr + 8 * i) * (DDIM / 4);

    // W staging: thread loads rows e = 32r + (tid>>3), float4 q = tid&7;
    // store slot XOR-swizzled: slot = q ^ (e&7)  (16B-aligned, bank-uniform)
    const int wrow = tid >> 3, wq = tid & 7;
    size_t wsrc[4]; int wdst[4];
#pragma unroll
    for (int r = 0; r < 4; ++r) {
        int e = 32 * r + wrow;
        wsrc[r] = (size_t)e * (DDIM / 4) + wq;
        wdst[r] = e * KB + 4 * (wq ^ (e & 7));
    }

    float4 sw[4];

    // ---- prologue: stage W tile 0 ----
#pragma unroll
    for (int r = 0; r < 4; ++r) sw[r] = W4[wsrc[r]];
#pragma unroll
    for (int r = 0; r < 4; ++r) *(float4*)&ws0[wdst[r]] = sw[r];
    __syncthreads();

    // ---- main K loop ----
    for (int t = 0; t < NTILES; ++t) {
        const float* wsc = ws0 + (t & 1) * (NEXP * KB);
        const bool more = (t + 1) < NTILES;
        if (more) {
#pragma unroll
            for (int r = 0; r < 4; ++r) sw[r] = W4[wsrc[r] + (t + 1) * 8];
        }

        const int kq0 = t * 8;
#pragma unroll
        for (int kq = 0; kq < 8; ++kq) {
            float4 xv[8], wv[4];
#pragma unroll
            for (int i = 0; i < 8; ++i) xv[i] = xp[i][kq0 + kq];
#pragma unroll
            for (int j = 0; j < 4; ++j)
                wv[j] = *(const float4*)&wsc[(ec + 32 * j) * KB + 4 * (kq ^ (ec & 7))];
            // accumulate strictly in (t, kq, x/y/z/w) order -> bit-identical to R0
#pragma unroll
            for (int i = 0; i < 8; ++i)
#pragma unroll
                for (int j = 0; j < 4; ++j) {
                    acc[i][j] += xv[i].x * wv[j].x;
                    acc[i][j] += xv[i].y * wv[j].y;
                    acc[i][j] += xv[i].z * wv[j].z;
                    acc[i][j] += xv[i].w * wv[j].w;
                }
        }

        if (more) {
            float* wsn = ws0 + ((t + 1) & 1) * (NEXP * KB);
#pragma unroll
            for (int r = 0; r < 4; ++r) *(float4*)&wsn[wdst[r]] = sw[r];
        }
        __syncthreads();
    }

    // ---- epilogue: logits -> LDS (overlay; GEMM tiles dead after final barrier) ----
#pragma unroll
    for (int i = 0; i < 8; ++i) {
        int m = tr + 8 * i;
#pragma unroll
        for (int j = 0; j < 4; ++j)
            lg[m * 132 + ec + 32 * j] = acc[i][j] + bv[j];
    }
    __syncthreads();

    // ---- partial top-8: 4 threads per token, 32 experts each ----
    {
        int tt = tid >> 2, p = tid & 3;
        float vals[8]; int idxs[8];
#pragma unroll
        for (int k = 0; k < 8; ++k) { vals[k] = -FLT_MAX; idxs[k] = 0; }
        const float* row = &lg[tt * 132 + p * 32];
        for (int q = 0; q < 32; ++q)
            insert8(vals, idxs, row[q], p * 32 + q);
#pragma unroll
        for (int k = 0; k < 8; ++k) {
            plv[tid * 8 + k] = vals[k];
            pli[tid * 8 + k] = idxs[k];
        }
    }
    __syncthreads();

    // ---- merge + softmax + index output (1 thread per token) ----
    float g[8]; int fidx[8];
    const bool active = (tid < MB);
    if (active) {
        float vals[8]; int idxs[8];
#pragma unroll
        for (int k = 0; k < 8; ++k) { vals[k] = -FLT_MAX; idxs[k] = 0; }
        for (int p = 0; p < 4; ++p) {
#pragma unroll
            for (int k = 0; k < 8; ++k)
                insert8(vals, idxs, plv[(tid * 4 + p) * 8 + k], pli[(tid * 4 + p) * 8 + k]);
        }
        float mx = vals[0];
        float s = 0.0f;
#pragma unroll
        for (int k = 0; k < 8; ++k) { g[k] = __expf(vals[k] - mx); s += g[k]; }
        float inv = 1.0f / s;
#pragma unroll
        for (int k = 0; k < 8; ++k) { g[k] *= inv; fidx[k] = idxs[k]; }
        // indices written as float values (whole out buffer is read back as f32)
#pragma unroll
        for (int k = 0; k < 8; ++k)
            out_idx[(size_t)(tok0 + tid) * KTOP + k] = (float)idxs[k];
    }
    // zero dense gate rows (merge no longer reads lg)
    for (int f = tid; f < MB * 132; f += 256) lg[f] = 0.0f;
    __syncthreads();

    if (active) {
#pragma unroll
        for (int k = 0; k < 8; ++k) lg[tid * 132 + fidx[k]] = g[k];
    }
    __syncthreads();

    // ---- coalesced dense copy-out ----
    for (int f = tid; f < MB * (NEXP / 4); f += 256) {
        int m = f >> 5, e4 = f & 31;
        float4 v = *(const float4*)&lg[m * 132 + e4 * 4];
        ((float4*)out_gates)[(size_t)(tok0 + m) * (NEXP / 4) + e4] = v;
    }
}

extern "C" void kernel_launch(void* const* d_in, const int* in_sizes, int n_in,
                              void* d_out, int out_size, void* d_ws, size_t ws_size,
                              hipStream_t stream) {
    const float* x = (const float*)d_in[0];   // [B,N,D] f32
    const float* W = (const float*)d_in[1];   // [E,D]   f32
    const float* b = (const float*)d_in[2];   // [E]     f32

    float* out_gates = (float*)d_out;                       // [B,N,E] f32
    float* out_idx   = out_gates + (size_t)TOKENS * NEXP;   // [B,N,K] as f32

    dim3 grid(TOKENS / MB);   // 256 blocks
    dim3 block(256);
    router_kernel<<<grid, block, 0, stream>>>(x, W, b, out_gates, out_idx);
}